// Round 1
// baseline (353.534 us; speedup 1.0000x reference)
//
#include <hip/hip_runtime.h>
#include <math.h>

// Dynamic_Loss on MI355X.
// Shapes: logit/ema_prob [8,20,512,512] f32, real_labels [8,512,512] i32,
// ema_thresh/moving_prob_avg [20] f32. Output: scalar f32.
//
// Factorization: loss = sum_c (1-new_mpa[c]) * Lsum[c] / n_valid, where
// Lsum[c] = sum over valid pixels with ema-class c of (lse - logit[c]).
// So one streaming pass accumulates 61 scalars; a 1-thread kernel finishes.
// ws layout (floats): [0..19] score sums, [20..39] counts, [40..59] loss sums,
// [60] valid count.

#define PASTC 15
#define NCC   20
#define IGN   255
#define HW2   262144          // 512*512 = 2^18
#define ALPHAF 0.99f

__global__ __launch_bounds__(256) void dl_main(
    const float* __restrict__ logit,
    const float* __restrict__ ema,
    const float* __restrict__ thresh,
    const int*   __restrict__ real,
    float*       __restrict__ ws)
{
    __shared__ float s_acc[61];
    const int tid = threadIdx.x;
    if (tid < 61) s_acc[tid] = 0.0f;
    __syncthreads();

    const int t  = blockIdx.x * 256 + tid;
    const int p0 = t << 2;                       // 4 pixels per thread
    const int b  = p0 >> 18;                     // batch
    const int s  = p0 & (HW2 - 1);               // spatial offset
    const size_t base = (((size_t)(b * NCC)) << 18) + (size_t)s;

    const int4 rl4 = *reinterpret_cast<const int4*>(real + p0);
    const int rl[4] = {rl4.x, rl4.y, rl4.z, rl4.w};

    // Capture channel for the score/eidx gather:
    //   real==255 -> channel 0; real in [15,19] -> channel real;
    //   real<15   -> -1 meaning "use argmax value" (gather == running max).
    int   cap_ch[4];
    float e_m15[4], e_cap[4];
    int   e_arg[4];
#pragma unroll
    for (int j = 0; j < 4; ++j) {
        cap_ch[j] = (rl[j] == IGN) ? 0 : (rl[j] >= PASTC ? rl[j] : -1);
        e_m15[j]  = -INFINITY;
        e_cap[j]  = 0.0f;
        e_arg[j]  = 0;
    }

    // ---------- EMA pass: argmax over first 15 ch + predicated gather ----------
#pragma unroll
    for (int c = 0; c < NCC; ++c) {
        const float4 v = *reinterpret_cast<const float4*>(ema + base + ((size_t)c << 18));
        const float vv[4] = {v.x, v.y, v.z, v.w};
#pragma unroll
        for (int j = 0; j < 4; ++j) {
            if (c < PASTC && vv[j] > e_m15[j]) { e_m15[j] = vv[j]; e_arg[j] = c; }
            if (c == cap_ch[j]) e_cap[j] = vv[j];
        }
    }

    int cidx[4];   // ema class for valid pixels, -1 otherwise
#pragma unroll
    for (int j = 0; j < 4; ++j) {
        const int   el  = (rl[j] >= PASTC) ? rl[j] : e_arg[j];       // 255 stays 255
        const float esc = (cap_ch[j] >= 0) ? e_cap[j] : e_m15[j];    // exact stored prob
        const float th  = thresh[el < NCC ? el : (NCC - 1)];
        const bool  valid = (el < NCC) && (esc >= th);
        cidx[j] = valid ? el : -1;
    }

    // ---------- logit pass: online softmax + argmax(0..14) + 2 gathers ----------
    float m20[4], se[4], m15[4], capS[4], capL[4];
    int   arg15[4];
#pragma unroll
    for (int j = 0; j < 4; ++j) {
        m20[j] = -INFINITY; se[j] = 0.0f; m15[j] = -INFINITY;
        capS[j] = 0.0f; capL[j] = 0.0f; arg15[j] = 0;
    }

#pragma unroll
    for (int c = 0; c < NCC; ++c) {
        const float4 v = *reinterpret_cast<const float4*>(logit + base + ((size_t)c << 18));
        const float vv[4] = {v.x, v.y, v.z, v.w};
#pragma unroll
        for (int j = 0; j < 4; ++j) {
            const float x  = vv[j];
            const float mo = m20[j];
            // one exp/channel online softmax: e = exp(-|x-m|)
            const float e  = __expf(-fabsf(x - mo));
            const bool  g  = x > mo;
            se[j]  = g ? fmaf(se[j], e, 1.0f) : (se[j] + e);
            m20[j] = fmaxf(mo, x);
            if (c < PASTC && x > m15[j]) { m15[j] = x; arg15[j] = c; }
            if (c == cap_ch[j]) capS[j] = x;
            if (c == cidx[j])   capL[j] = x;
        }
    }

    // ---------- per-pixel epilogue -> LDS bins ----------
#pragma unroll
    for (int j = 0; j < 4; ++j) {
        const float lse = m20[j] + __logf(se[j]);
        if (rl[j] != IGN) {
            const int   lab  = (rl[j] >= PASTC) ? rl[j] : arg15[j];   // in [0,19]
            const float sval = (cap_ch[j] >= 0) ? capS[j] : m15[j];
            const float prob = __expf(sval - lse);
            atomicAdd(&s_acc[lab], prob);
            atomicAdd(&s_acc[20 + lab], 1.0f);
        }
        if (cidx[j] >= 0) {
            atomicAdd(&s_acc[40 + cidx[j]], lse - capL[j]);
        }
        // valid count: one LDS atomic per wave via ballot
        const unsigned long long bm = __ballot(cidx[j] >= 0);
        if ((tid & 63) == 0) atomicAdd(&s_acc[60], (float)__popcll(bm));
    }

    __syncthreads();
    if (tid < 61) atomicAdd(&ws[tid], s_acc[tid]);
}

__global__ void dl_final(const float* __restrict__ ws,
                         const float* __restrict__ mpa,
                         float*       __restrict__ out)
{
    if (threadIdx.x == 0 && blockIdx.x == 0) {
        float acc = 0.0f;
        for (int c = 0; c < NCC; ++c) {
            const float ssum = ws[c];
            const float cnt  = ws[20 + c];
            const float lsum = ws[40 + c];
            const float m    = mpa[c];
            const float mean = ssum / fmaxf(cnt, 1.0f);
            const float nm   = (cnt > 0.0f)
                                 ? ((m == -1.0f) ? mean
                                                 : (1.0f - ALPHAF) * mean + ALPHAF * m)
                                 : m;
            acc += lsum * (1.0f - nm);
        }
        out[0] = acc / ws[60];
    }
}

extern "C" void kernel_launch(void* const* d_in, const int* in_sizes, int n_in,
                              void* d_out, int out_size, void* d_ws, size_t ws_size,
                              hipStream_t stream) {
    const float* logit  = (const float*)d_in[0];
    const float* ema    = (const float*)d_in[1];
    const float* thresh = (const float*)d_in[2];
    const int*   real   = (const int*)d_in[3];
    const float* mpa    = (const float*)d_in[4];
    float* out = (float*)d_out;
    float* ws  = (float*)d_ws;

    // ws is re-poisoned to 0xAA before every timed launch; zero the 61 bins.
    hipMemsetAsync(ws, 0, 64 * sizeof(float), stream);

    // 2,097,152 pixels / 4 per thread / 256 per block = 2048 blocks (exact)
    dl_main<<<2048, 256, 0, stream>>>(logit, ema, thresh, real, ws);
    dl_final<<<1, 64, 0, stream>>>(ws, mpa, out);
}